// Round 9
// baseline (312.824 us; speedup 1.0000x reference)
//
#include <hip/hip_runtime.h>
#include <hip/hip_bf16.h>
#include <cstdint>

typedef unsigned short u16;
typedef unsigned int u32;
typedef __bf16 bf16x8 __attribute__((ext_vector_type(8)));
typedef u16 u16x8 __attribute__((ext_vector_type(8)));
typedef u16 u16x4 __attribute__((ext_vector_type(4)));
typedef float f32x4 __attribute__((ext_vector_type(4)));

#define MFMA16(a, b, c) __builtin_amdgcn_mfma_f32_16x16x32_bf16(a, b, c, 0, 0, 0)

__device__ __forceinline__ void async16(const void* g, void* s) {
    __builtin_amdgcn_global_load_lds((const __attribute__((address_space(1))) void*)g,
                                     (__attribute__((address_space(3))) void*)s, 16, 0, 0);
}

__device__ __forceinline__ u16 f2bf(float f) {
    u32 u; __builtin_memcpy(&u, &f, 4);
    u = u + 0x7fffu + ((u >> 16) & 1u);
    return (u16)(u >> 16);
}

// ---------------------------------------------------------------------------
// Fused prep: blocks [0,9216) = input converts (f32->bf16, 8/thread);
// blocks [9216,10240) = weight transpose-converts. One dispatch.
// ---------------------------------------------------------------------------
__global__ __launch_bounds__(256) void prep_all(const float* __restrict__ inq,
                                                u16* __restrict__ Aq,
                                                const float* __restrict__ inkv,
                                                u16* __restrict__ Akv,
                                                const float* __restrict__ Wq,  u16* __restrict__ WqT,
                                                const float* __restrict__ Wkv, u16* __restrict__ WkvT,
                                                const float* __restrict__ Wp,  u16* __restrict__ WpT) {
    __shared__ u16 t[64][65];
    const int blk = blockIdx.x;
    const int tid = threadIdx.x;
    if (blk < 9216) {
        const float* in; u16* out; size_t i;
        if (blk < 1024) { in = inq;  out = Aq;  i = (size_t)blk * 256 + tid; }
        else            { in = inkv; out = Akv; i = (size_t)(blk - 1024) * 256 + tid; }
        const float4* p = (const float4*)in + i * 2;
        const float4 a = p[0], b = p[1];
        u16x8 v;
        v[0] = f2bf(a.x); v[1] = f2bf(a.y); v[2] = f2bf(a.z); v[3] = f2bf(a.w);
        v[4] = f2bf(b.x); v[5] = f2bf(b.y); v[6] = f2bf(b.z); v[7] = f2bf(b.w);
        ((u16x8*)out)[i] = v;
        return;
    }
    const int wblk = blk - 9216;
    const float* in; u16* out; int R, C, bx, by;
    if (wblk < 256)      { in = Wq;  out = WqT;  R = 1024; C = 1024; bx = wblk & 15;  by = wblk >> 4; }
    else if (wblk < 768) { in = Wkv; out = WkvT; R = 1024; C = 2048; bx = (wblk - 256) & 31; by = (wblk - 256) >> 5; }
    else                 { in = Wp;  out = WpT;  R = 1024; C = 1024; bx = (wblk - 768) & 15; by = (wblk - 768) >> 4; }
    const int r0 = by << 6, c0 = bx << 6;
#pragma unroll
    for (int i = 0; i < 16; i++) {
        int idx = i * 256 + tid;
        int r = idx >> 6, c = idx & 63;
        t[r][c] = f2bf(in[(size_t)(r0 + r) * C + c0 + c]);
    }
    __syncthreads();
#pragma unroll
    for (int i = 0; i < 16; i++) {
        int idx = i * 256 + tid;
        int c = idx >> 6, r = idx & 63;
        out[(size_t)(c0 + c) * R + r0 + r] = t[r][c];
    }
}

// ---------------------------------------------------------------------------
// GEMM: C(MxN) = A(MxK) * B^T(NxK), bf16 in, fp32 acc. 128-tile, BK=64,
// 2-barrier structure. Used for the small q / out-proj GEMMs only.
// MFMA operands SWAPPED (acc transposed) -> column-packed vector stores.
// ---------------------------------------------------------------------------
template <bool OUTF32, int NT>
__global__ __launch_bounds__(256) void gemm_bt(const u16* __restrict__ A,
                                               const u16* __restrict__ B,
                                               void* __restrict__ Cv,
                                               const float* __restrict__ bias,
                                               int M, int N, int K) {
    constexpr int NJ = NT / 32;
    __shared__ __align__(16) u16 As[128 * 64];
    __shared__ __align__(16) u16 Bs[NT * 64];
    const int tid = threadIdx.x;
    const int wave = tid >> 6, lane = tid & 63;
    const int lrow = lane & 15, quad = lane >> 4;
    const int nb = N / NT;
    const int bx = blockIdx.x % nb, by = blockIdx.x / nb;
    const long m0 = (long)by << 7, n0 = (long)bx * NT;
    const int wm = (wave >> 1) << 6, wn = (wave & 1) * (NT / 2);

    const f32x4 fz = {0.f, 0.f, 0.f, 0.f};
    f32x4 acc[4][NJ];
#pragma unroll
    for (int i = 0; i < 4; i++)
#pragma unroll
        for (int j = 0; j < NJ; j++) acc[i][j] = fz;

    const int srow = wave * 8 + (lane >> 3);
    const int scol = ((lane & 7) ^ (lane >> 3)) << 3;
    const u16* Ag = A + (m0 + srow) * K + scol;
    const u16* Bg = B + (n0 + srow) * K + scol;
    u16* AsW = &As[wave * 512];
    u16* BsW = &Bs[wave * 512];

    for (int k0 = 0; k0 < K; k0 += 64) {
        __syncthreads();
#pragma unroll
        for (int c = 0; c < 4; c++)
            async16(Ag + (long)c * 32 * K + k0, AsW + c * 2048);
#pragma unroll
        for (int c = 0; c < NT / 32; c++)
            async16(Bg + (long)c * 32 * K + k0, BsW + c * 2048);
        __syncthreads();
#pragma unroll
        for (int c = 0; c < 2; c++) {
            bf16x8 af[4], bfr[NJ];
#pragma unroll
            for (int i = 0; i < 4; i++) {
                const int row = wm + i * 16 + lrow;
                af[i] = *(const bf16x8*)&As[row * 64 + (((c * 4 + quad) ^ (row & 7)) << 3)];
            }
#pragma unroll
            for (int j = 0; j < NJ; j++) {
                const int row = wn + j * 16 + lrow;
                bfr[j] = *(const bf16x8*)&Bs[row * 64 + (((c * 4 + quad) ^ (row & 7)) << 3)];
            }
#pragma unroll
            for (int i = 0; i < 4; i++)
#pragma unroll
                for (int j = 0; j < NJ; j++)
                    acc[i][j] = MFMA16(bfr[j], af[i], acc[i][j]);   // swapped
        }
    }
    // epilogue (transposed acc): row = m0+wm+i*16+lrow, cols = n0+wn+j*16+quad*4 .. +3
#pragma unroll
    for (int i = 0; i < 4; i++) {
        const long row = m0 + wm + i * 16 + lrow;
#pragma unroll
        for (int j = 0; j < NJ; j++) {
            const long colb = n0 + wn + j * 16 + quad * 4;
            if (OUTF32) {
                f32x4 v = acc[i][j];
                if (bias) v += *(const f32x4*)&bias[colb];
                *(f32x4*)&((float*)Cv)[row * N + colb] = v;
            } else {
                u16x4 pk;
#pragma unroll
                for (int r = 0; r < 4; r++) pk[r] = f2bf(acc[i][j][r]);
                *(u16x4*)&((u16*)Cv)[row * N + colb] = pk;
            }
        }
    }
}

// ---------------------------------------------------------------------------
// KV-projection GEMM, 256x256 tile, 8 waves, counted-vmcnt 4-phase schedule
// (frozen). K-half waves run operand-SWAPPED MFMA (transposed acc).
// LDS-bounce epilogue: after the K-loop, reuse As (64 KB) as scratch to
// assemble full cache lines — V pass writes Vt rows as 512 B contiguous
// runs, K pass writes kvbuf row segments as 256 B runs. Kills the 2.3x
// write amplification of the direct scattered stores (WRITE 74 -> ~36 MB).
// ---------------------------------------------------------------------------
__global__ __launch_bounds__(512, 2) void gemm_kv256(const u16* __restrict__ A,
                                                     const u16* __restrict__ B,
                                                     u16* __restrict__ C,
                                                     u16* __restrict__ Vt) {
    constexpr int K = 1024, N = 2048, NT = 16;  // NT = K/64 K-tiles
    __shared__ __align__(16) u16 As[2][256 * 64];
    __shared__ __align__(16) u16 Bs[2][256 * 64];
    const int tid = threadIdx.x;
    const int wave = tid >> 6, lane = tid & 63;
    const int lrow = lane & 15, quad = lane >> 4;
    const int wMi = wave >> 2, wNi = wave & 3;
    const int wm = wMi * 128, wn = wNi * 64;
    const bool kswap = (wNi < 2);
    // bijective XCD swizzle: 512 wgs, 8 XCDs, 64 contiguous tiles each
    const int wg = blockIdx.x;
    const int swz = (wg & 7) * 64 + (wg >> 3);
    const int bx = swz & 7, by = swz >> 3;
    const long m0 = (long)by << 8, n0 = (long)bx << 8;

    const int srow = tid >> 3;
    const int scol = ((tid & 7) ^ (srow & 7)) << 3;
    const u16* Ag = A + (m0 + srow) * K + scol;
    const u16* Bg = B + (n0 + srow) * K + scol;
    const int sdst = tid * 8;

    auto stgA = [&](int bi, int h, int kt) {
        async16(Ag + (size_t)(h * 128) * K + kt * 64,      &As[bi][h * 8192 + sdst]);
        async16(Ag + (size_t)(h * 128 + 64) * K + kt * 64, &As[bi][h * 8192 + 4096 + sdst]);
    };
    auto stgB = [&](int bi, int h, int kt) {
        async16(Bg + (size_t)(h * 128) * K + kt * 64,      &Bs[bi][h * 8192 + sdst]);
        async16(Bg + (size_t)(h * 128 + 64) * K + kt * 64, &Bs[bi][h * 8192 + 4096 + sdst]);
    };

    // prologue: t0{Blo,Bhi,Alo,Ahi}, t1{Blo,Bhi,Alo}; vmcnt(6) => t0 landed
    stgB(0, 0, 0); stgB(0, 1, 0); stgA(0, 0, 0); stgA(0, 1, 0);
    stgB(1, 0, 1); stgB(1, 1, 1); stgA(1, 0, 1);

    const f32x4 fz = {0.f, 0.f, 0.f, 0.f};
    f32x4 acc[8][4];
#pragma unroll
    for (int i = 0; i < 8; i++)
#pragma unroll
        for (int j = 0; j < 4; j++) acc[i][j] = fz;

    asm volatile("s_waitcnt vmcnt(6)" ::: "memory");
    __builtin_amdgcn_s_barrier();

    bf16x8 av[4][2], bv[4][2];
    // MFMA cluster helper: rows i0..i0+3 (acc index base ib), cols j0..j0+1
    auto cluster = [&](int ib, int j0) {
        if (kswap) {
#pragma unroll
            for (int i = 0; i < 4; i++)
#pragma unroll
                for (int j = j0; j < j0 + 2; j++)
#pragma unroll
                    for (int c = 0; c < 2; c++)
                        acc[ib + i][j] = MFMA16(bv[j][c], av[i][c], acc[ib + i][j]);
        } else {
#pragma unroll
            for (int i = 0; i < 4; i++)
#pragma unroll
                for (int j = j0; j < j0 + 2; j++)
#pragma unroll
                    for (int c = 0; c < 2; c++)
                        acc[ib + i][j] = MFMA16(av[i][c], bv[j][c], acc[ib + i][j]);
        }
    };

    for (int t = 0; t < NT; ++t) {
        const int cur = t & 1, nxt = cur ^ 1;
        // ---- phase 1: ds_read A(i0-3) + B(all 8); stage (t+1).Ahi; MFMA i0-3 x j0-1
#pragma unroll
        for (int i = 0; i < 4; i++) {
            const int row = wm + i * 16 + lrow;
#pragma unroll
            for (int c = 0; c < 2; c++)
                av[i][c] = *(const bf16x8*)&As[cur][row * 64 + (((c * 4 + quad) ^ (row & 7)) << 3)];
        }
#pragma unroll
        for (int j = 0; j < 4; j++) {
            const int row = wn + j * 16 + lrow;
#pragma unroll
            for (int c = 0; c < 2; c++)
                bv[j][c] = *(const bf16x8*)&Bs[cur][row * 64 + (((c * 4 + quad) ^ (row & 7)) << 3)];
        }
        if (t + 1 < NT) stgA(nxt, 1, t + 1);
        __builtin_amdgcn_s_barrier();
        asm volatile("s_waitcnt lgkmcnt(0)" ::: "memory");
        __builtin_amdgcn_sched_barrier(0);
        __builtin_amdgcn_s_setprio(1);
        cluster(0, 0);
        __builtin_amdgcn_s_setprio(0);
        __builtin_amdgcn_s_barrier();
        // ---- phase 2: stage (t+2).Blo; MFMA i0-3 x j2-3 (regs only)
        if (t + 2 < NT) stgB(cur, 0, t + 2);
        __builtin_amdgcn_s_barrier();
        __builtin_amdgcn_sched_barrier(0);
        __builtin_amdgcn_s_setprio(1);
        cluster(0, 2);
        __builtin_amdgcn_s_setprio(0);
        __builtin_amdgcn_s_barrier();
        // ---- phase 3: ds_read A(i4-7); stage (t+2).Bhi; MFMA i4-7 x j0-1
#pragma unroll
        for (int i = 0; i < 4; i++) {
            const int row = wm + (i + 4) * 16 + lrow;
#pragma unroll
            for (int c = 0; c < 2; c++)
                av[i][c] = *(const bf16x8*)&As[cur][row * 64 + (((c * 4 + quad) ^ (row & 7)) << 3)];
        }
        if (t + 2 < NT) stgB(cur, 1, t + 2);
        __builtin_amdgcn_s_barrier();
        asm volatile("s_waitcnt lgkmcnt(0)" ::: "memory");
        __builtin_amdgcn_sched_barrier(0);
        __builtin_amdgcn_s_setprio(1);
        cluster(4, 0);
        __builtin_amdgcn_s_setprio(0);
        __builtin_amdgcn_s_barrier();
        // ---- phase 4: stage (t+2).Alo; MFMA i4-7 x j2-3; counted vmcnt
        if (t + 2 < NT) stgA(cur, 0, t + 2);
        __builtin_amdgcn_s_barrier();
        __builtin_amdgcn_sched_barrier(0);
        __builtin_amdgcn_s_setprio(1);
        cluster(4, 2);
        __builtin_amdgcn_s_setprio(0);
        if (t + 2 < NT)      { asm volatile("s_waitcnt vmcnt(6)" ::: "memory"); }
        else if (t + 1 < NT) { asm volatile("s_waitcnt vmcnt(0)" ::: "memory"); }
        __builtin_amdgcn_s_barrier();
    }

    // ---- LDS-bounce epilogue. Tile = head bx; batch b fixed per tile.
    const int h = bx;
    const int b = (int)(m0 >> 12), kv0 = (int)(m0 & 4095);
    u16* scr = &As[0][0];   // 64 KB scratch (K-loop staging fully drained)

    // V pass: V-waves (normal acc: lane=dh, regs=kv) dump -> scr[dh][kv 256]
    if (!kswap) {
#pragma unroll
        for (int j = 0; j < 4; j++) {
            const int dh = (wNi - 2) * 64 + j * 16 + lrow;
            const int sw = (dh & 7) << 3;
#pragma unroll
            for (int i = 0; i < 8; i++) {
                const int kvl = wm + i * 16 + quad * 4;
                u16x4 pk;
#pragma unroll
                for (int r = 0; r < 4; r++) pk[r] = f2bf(acc[i][j][r]);
                *(u16x4*)&scr[dh * 256 + (kvl ^ sw)] = pk;
            }
        }
    }
    __syncthreads();
    // all 512 threads copy V out: thread -> (dh, 64-elem segment), 512 B runs
    {
        const int dh = tid >> 2, seg = tid & 3;
        const int sw = (dh & 7) << 3;
        u16* dst = &Vt[(((size_t)b * 8 + h) * 128 + dh) * 4096 + kv0 + seg * 64];
        const u16* srcb = &scr[dh * 256 + seg * 64];
#pragma unroll
        for (int c = 0; c < 8; c++)
            *(u16x8*)(dst + c * 8) = *(const u16x8*)&srcb[(c * 8) ^ sw];
    }
    __syncthreads();
    // K pass: K-waves (swapped acc: lane=kv, regs=dh) dump -> scr[kv 256][dh]
    if (kswap) {
#pragma unroll
        for (int i = 0; i < 8; i++) {
            const int kvl = wm + i * 16 + lrow;
            const int sw = (kvl & 7) << 3;
#pragma unroll
            for (int j = 0; j < 4; j++) {
                const int dh = wn + j * 16 + quad * 4;
                u16x4 pk;
#pragma unroll
                for (int r = 0; r < 4; r++) pk[r] = f2bf(acc[i][j][r]);
                *(u16x4*)&scr[kvl * 128 + (dh ^ sw)] = pk;
            }
        }
    }
    __syncthreads();
    // all 512 threads copy K out: thread -> (kv row, 64-elem half), 256 B runs
    {
        const int kvl = tid >> 1, half = tid & 1;
        const int sw = (kvl & 7) << 3;
        u16* dst = &C[(m0 + kvl) * N + n0 + half * 64];
        const u16* srcb = &scr[kvl * 128 + half * 64];
#pragma unroll
        for (int c = 0; c < 8; c++)
            *(u16x8*)(dst + c * 8) = *(const u16x8*)&srcb[(c * 8) ^ sw];
    }
}

// ---------------------------------------------------------------------------
// Split-K flash attention (r6 best): kvbuf K reads, XCD chunking
// blk=(p&7)*64+(p>>3), double-buffered K/V LDS, T14 reg prefetch,
// 1 barrier/iter, defer-max, setprio. LDS 80 KiB -> 2 blocks/CU.
// ---------------------------------------------------------------------------
__global__ __launch_bounds__(512, 4) void flash_attn_split(const u16* __restrict__ qb,
                                                           const u16* __restrict__ kvb,
                                                           const u16* __restrict__ vTb,
                                                           float* __restrict__ Opart,
                                                           float* __restrict__ Mpart,
                                                           float* __restrict__ Lpart) {
    __shared__ __align__(16) u16 Ks[2][64 * 128];    // [kv][dh], blk^(kv&15) swizzle
    __shared__ __align__(16) u16 Vs[2][128 * 64];    // [dh][kv], blk^(dh&7) swizzle
    __shared__ __align__(16) u16 Ps[8][16 * 64];     // per-wave [q][kv]
    const int tid = threadIdx.x, wave = tid >> 6, lane = tid & 63;
    const int lrow = lane & 15, quad = lane >> 4;
    const int p = blockIdx.x;
    const int blk = (p & 7) * 64 + (p >> 3);         // logical id, XCD-chunked
    const int split = blk & 3, qt = (blk >> 2) & 3, h = (blk >> 4) & 7, b = blk >> 7;
    const int q0 = qt * 128;
    const int kbase = split * 1024;

    bf16x8 qf[4];
    {
        const u16* qp = qb + (((size_t)(b * 512 + q0 + wave * 16 + lrow) * 8 + h) << 7) + quad * 8;
#pragma unroll
        for (int c = 0; c < 4; c++) qf[c] = *(const bf16x8*)(qp + c * 32);
    }

    const f32x4 fz = {0.f, 0.f, 0.f, 0.f};
    f32x4 oacc[8];
#pragma unroll
    for (int g = 0; g < 8; g++) oacc[g] = fz;
    float mrow = -1e30f, lsum = 0.f;
    const float scale = 0.08838834764831845f;

    const int kRow = tid >> 4, kBlk = tid & 15;   // K: rows kRow, kRow+32
    const int vRow = tid >> 3, vBlk = tid & 7;    // V: rows vRow, vRow+64
    const u16* kg = kvb + (size_t)b * 4096 * 2048 + h * 256 + kBlk * 8;
    const u16* vg = vTb + (size_t)(b * 8 + h) * 128 * 4096 + vBlk * 8;
    const int ksw = (kBlk ^ (kRow & 15)) << 3;    // same swizzle for row kRow+32
    const int vsw = (vBlk ^ (vRow & 7)) << 3;     // same swizzle for row vRow+64

    // prologue: stage tile 0 into buf 0
    {
        const bf16x8 a0 = *(const bf16x8*)&kg[(size_t)(kbase + kRow) * 2048];
        const bf16x8 a1 = *(const bf16x8*)&kg[(size_t)(kbase + 32 + kRow) * 2048];
        const bf16x8 b0 = *(const bf16x8*)&vg[(size_t)vRow * 4096 + kbase];
        const bf16x8 b1 = *(const bf16x8*)&vg[(size_t)(64 + vRow) * 4096 + kbase];
        *(bf16x8*)&Ks[0][kRow * 128 + ksw] = a0;
        *(bf16x8*)&Ks[0][(32 + kRow) * 128 + ksw] = a1;
        *(bf16x8*)&Vs[0][vRow * 64 + vsw] = b0;
        *(bf16x8*)&Vs[0][(64 + vRow) * 64 + vsw] = b1;
    }
    __syncthreads();

    for (int it = 0; it < 16; ++it) {
        const int cur = it & 1, nxt = cur ^ 1;
        const bool more = (it + 1 < 16);
        // T14: issue next-tile loads early; latency hides under QK+softmax+PV
        bf16x8 nk0, nk1, nv0, nv1;
        if (more) {
            const int k1 = kbase + (it + 1) * 64;
            nk0 = *(const bf16x8*)&kg[(size_t)(k1 + kRow) * 2048];
            nk1 = *(const bf16x8*)&kg[(size_t)(k1 + 32 + kRow) * 2048];
            nv0 = *(const bf16x8*)&vg[(size_t)vRow * 4096 + k1];
            nv1 = *(const bf16x8*)&vg[(size_t)(64 + vRow) * 4096 + k1];
        }

        // QK^T on Ks[cur]
        f32x4 s[4];
        __builtin_amdgcn_s_setprio(1);
#pragma unroll
        for (int t = 0; t < 4; t++) {
            f32x4 a = fz;
#pragma unroll
            for (int c = 0; c < 4; c++) {
                const bf16x8 kf = *(const bf16x8*)
                    &Ks[cur][(t * 16 + lrow) * 128 + (((c * 4 + quad) ^ lrow) << 3)];
                a = MFMA16(kf, qf[c], a);
            }
            s[t] = a * scale;
        }
        __builtin_amdgcn_s_setprio(0);

        // online softmax with defer-max (T13, THR=8)
        float mx = s[0][0];
#pragma unroll
        for (int t = 0; t < 4; t++)
#pragma unroll
            for (int r = 0; r < 4; r++) mx = fmaxf(mx, s[t][r]);
        mx = fmaxf(mx, __shfl_xor(mx, 16));
        mx = fmaxf(mx, __shfl_xor(mx, 32));
        float mn = fmaxf(mrow, mx);
        if (__all(mx <= mrow + 8.f)) {
            mn = mrow;                       // defer: keep old max, no rescale
        } else {
            const float alpha = __expf(mrow - mn);
#pragma unroll
            for (int g = 0; g < 8; g++) oacc[g] *= alpha;
            lsum *= alpha;
            mrow = mn;
        }
        float sum = 0.f;
#pragma unroll
        for (int t = 0; t < 4; t++)
#pragma unroll
            for (int r = 0; r < 4; r++) {
                float pv = __expf(s[t][r] - mn);
                s[t][r] = pv;
                sum += pv;
            }
        sum += __shfl_xor(sum, 16);
        sum += __shfl_xor(sum, 32);
        lsum += sum;

        // P pack -> per-wave LDS, then PV on Vs[cur]
        u16* Pw = &Ps[wave][0];
#pragma unroll
        for (int t = 0; t < 4; t++) {
            u16x4 pk;
#pragma unroll
            for (int r = 0; r < 4; r++) pk[r] = f2bf(s[t][r]);
            const int kvo = t * 16 + quad * 4;
            *(u16x4*)&Pw[lrow * 64 + (((kvo >> 3) ^ (lrow & 7)) << 3) + (kvo & 7)] = pk;
        }
        asm volatile("s_waitcnt lgkmcnt(0)" ::: "memory");
        __builtin_amdgcn_sched_barrier(0);
        const bf16x8 pf0 = *(const bf16x8*)&Pw[lrow * 64 + ((quad ^ (lrow & 7)) << 3)];
        const bf16x8 pf1 = *(const bf16x8*)&Pw[lrow * 64 + (((4 + quad) ^ (lrow & 7)) << 3)];

        __builtin_amdgcn_s_setprio(1);
#pragma unroll
        for (int g = 0; g < 8; g++) {
            f32x4 o = oacc[g];
            o = MFMA16(*(const bf16x8*)&Vs[cur][(g * 16 + lrow) * 64 + ((quad ^ (lrow & 7)) << 3)], pf0, o);
            o = MFMA16(*(const bf16x8*)&Vs[cur][(g * 16 + lrow) * 64 + (((4 + quad) ^ (lrow & 7)) << 3)], pf1, o);
            oacc[g] = o;
        }
        __builtin_amdgcn_s_setprio(0);

        // write next tile into the other buffer (its readers finished before
        // the previous iteration's barrier)
        if (more) {
            *(bf16x8*)&Ks[nxt][kRow * 128 + ksw] = nk0;
            *(bf16x8*)&Ks[nxt][(32 + kRow) * 128 + ksw] = nk1;
            *(bf16x8*)&Vs[nxt][vRow * 64 + vsw] = nv0;
            *(bf16x8*)&Vs[nxt][(64 + vRow) * 64 + vsw] = nv1;
        }
        __syncthreads();
    }

    // unnormalized partials: Ob[q*128 + dh] (indexed by LOGICAL blk)
    float* Ob = Opart + (size_t)blk * 16384;
#pragma unroll
    for (int g = 0; g < 8; g++)
        *(f32x4*)&Ob[(wave * 16 + lrow) * 128 + g * 16 + quad * 4] = oacc[g];
    if (quad == 0) {
        const int row = blk * 128 + wave * 16 + lrow;
        Mpart[row] = mrow;
        Lpart[row] = lsum;
    }
}

// ---------------------------------------------------------------------------
// Combine 4 split partials -> obuf (B,Q,H,128) bf16.
// grid 128 (= (b*8+h)*4+qt), 512 threads: 128 rows x 4 col-groups of 32.
// ---------------------------------------------------------------------------
__global__ __launch_bounds__(512) void combine_attn(const float* __restrict__ Opart,
                                                    const float* __restrict__ Mpart,
                                                    const float* __restrict__ Lpart,
                                                    u16* __restrict__ ob) {
    const int c = blockIdx.x;
    const int qt = c & 3, h = (c >> 2) & 7, b = c >> 5;
    const int lr = threadIdx.x >> 2, cg = (threadIdx.x & 3) * 32;
    float ms[4], w[4];
    float m = -1e30f;
#pragma unroll
    for (int s = 0; s < 4; s++) { ms[s] = Mpart[(c * 4 + s) * 128 + lr]; m = fmaxf(m, ms[s]); }
    float l = 0.f;
#pragma unroll
    for (int s = 0; s < 4; s++) { w[s] = __expf(ms[s] - m); l += w[s] * Lpart[(c * 4 + s) * 128 + lr]; }
    const float inv = 1.f / l;
#pragma unroll
    for (int s = 0; s < 4; s++) w[s] *= inv;
    const size_t orow = ((size_t)(b * 512 + qt * 128 + lr) * 8 + h) << 7;
#pragma unroll
    for (int j = 0; j < 4; j++) {
        f32x4 a0 = {0.f, 0.f, 0.f, 0.f}, a1 = a0;
#pragma unroll
        for (int s = 0; s < 4; s++) {
            const f32x4* pp = (const f32x4*)(Opart + ((size_t)(c * 4 + s)) * 16384 + (size_t)lr * 128 + cg + j * 8);
            a0 += pp[0] * w[s];
            a1 += pp[1] * w[s];
        }
        u16x8 v;
#pragma unroll
        for (int i = 0; i < 4; i++) { v[i] = f2bf(a0[i]); v[4 + i] = f2bf(a1[i]); }
        *(u16x8*)&ob[orow + cg + j * 8] = v;
    }
}

// ---------------------------------------------------------------------------
extern "C" void kernel_launch(void* const* d_in, const int* in_sizes, int n_in,
                              void* d_out, int out_size, void* d_ws, size_t ws_size,
                              hipStream_t stream) {
    const float* inq   = (const float*)d_in[0];
    const float* inkv  = (const float*)d_in[1];
    const float* Wq    = (const float*)d_in[2];
    const float* Wkv   = (const float*)d_in[3];
    const float* Wproj = (const float*)d_in[4];
    const float* bproj = (const float*)d_in[5];
    float* out = (float*)d_out;

    u16* WqT    = (u16*)d_ws;                          // 1M elems
    u16* WkvT   = WqT + (size_t)1024 * 1024;           // 2M
    u16* WprojT = WkvT + (size_t)2048 * 1024;          // 1M
    u16* Aq     = WprojT + (size_t)1024 * 1024;        // 2M   bf16(inputs_q); dead after q-gemm
    u16* Akv    = Aq + (size_t)2048 * 1024;            // 16M  bf16(inputs_kv); dead after kv-gemm
    u16* qbuf   = Akv + (size_t)16384 * 1024;          // 2M   (B,Q,H,DH)
    u16* kvbuf  = qbuf + (size_t)2048 * 1024;          // 32M  (B,K,H,2DH) K-half valid
    u16* vTbuf  = kvbuf + (size_t)16384 * 2048;        // 16M  (B,H,DH,K)
    u16* obuf   = vTbuf + (size_t)32 * 128 * 4096;     // 2M   (B,Q,H,DH)

    float* Opart = (float*)Akv;                        // 512*16384 f32 = 32 MB
    float* Mpart = (float*)Aq;                         // 64K f32
    float* Lpart = Mpart + 65536;                      // 64K f32

    prep_all<<<10240, 256, 0, stream>>>(inq, Aq, inkv, Akv, Wq, WqT, Wkv, WkvT, Wproj, WprojT);

    gemm_bt<false, 64><<<16 * 16, 256, 0, stream>>>(Aq, WqT, qbuf, nullptr, 2048, 1024, 1024);
    gemm_kv256<<<512, 512, 0, stream>>>(Akv, WkvT, kvbuf, vTbuf);

    flash_attn_split<<<512, 512, 0, stream>>>(qbuf, kvbuf, vTbuf, Opart, Mpart, Lpart);
    combine_attn<<<128, 512, 0, stream>>>(Opart, Mpart, Lpart, obuf);

    gemm_bt<true, 64><<<16 * 16, 256, 0, stream>>>(obuf, WprojT, (void*)out, bproj, 2048, 1024, 1024);
}

// Round 10
// 301.820 us; speedup vs baseline: 1.0365x; 1.0365x over previous
//
#include <hip/hip_runtime.h>
#include <hip/hip_bf16.h>
#include <cstdint>

typedef unsigned short u16;
typedef unsigned int u32;
typedef __bf16 bf16x8 __attribute__((ext_vector_type(8)));
typedef u16 u16x8 __attribute__((ext_vector_type(8)));
typedef u16 u16x4 __attribute__((ext_vector_type(4)));
typedef float f32x4 __attribute__((ext_vector_type(4)));

#define MFMA16(a, b, c) __builtin_amdgcn_mfma_f32_16x16x32_bf16(a, b, c, 0, 0, 0)

__device__ __forceinline__ void async16(const void* g, void* s) {
    __builtin_amdgcn_global_load_lds((const __attribute__((address_space(1))) void*)g,
                                     (__attribute__((address_space(3))) void*)s, 16, 0, 0);
}

__device__ __forceinline__ u16 f2bf(float f) {
    u32 u; __builtin_memcpy(&u, &f, 4);
    u = u + 0x7fffu + ((u >> 16) & 1u);
    return (u16)(u >> 16);
}

// ---------------------------------------------------------------------------
// Fused prep: blocks [0,9216) = input converts (f32->bf16, 8/thread);
// blocks [9216,10240) = weight transpose-converts. One dispatch.
// ---------------------------------------------------------------------------
__global__ __launch_bounds__(256) void prep_all(const float* __restrict__ inq,
                                                u16* __restrict__ Aq,
                                                const float* __restrict__ inkv,
                                                u16* __restrict__ Akv,
                                                const float* __restrict__ Wq,  u16* __restrict__ WqT,
                                                const float* __restrict__ Wkv, u16* __restrict__ WkvT,
                                                const float* __restrict__ Wp,  u16* __restrict__ WpT) {
    __shared__ u16 t[64][65];
    const int blk = blockIdx.x;
    const int tid = threadIdx.x;
    if (blk < 9216) {
        const float* in; u16* out; size_t i;
        if (blk < 1024) { in = inq;  out = Aq;  i = (size_t)blk * 256 + tid; }
        else            { in = inkv; out = Akv; i = (size_t)(blk - 1024) * 256 + tid; }
        const float4* p = (const float4*)in + i * 2;
        const float4 a = p[0], b = p[1];
        u16x8 v;
        v[0] = f2bf(a.x); v[1] = f2bf(a.y); v[2] = f2bf(a.z); v[3] = f2bf(a.w);
        v[4] = f2bf(b.x); v[5] = f2bf(b.y); v[6] = f2bf(b.z); v[7] = f2bf(b.w);
        ((u16x8*)out)[i] = v;
        return;
    }
    const int wblk = blk - 9216;
    const float* in; u16* out; int R, C, bx, by;
    if (wblk < 256)      { in = Wq;  out = WqT;  R = 1024; C = 1024; bx = wblk & 15;  by = wblk >> 4; }
    else if (wblk < 768) { in = Wkv; out = WkvT; R = 1024; C = 2048; bx = (wblk - 256) & 31; by = (wblk - 256) >> 5; }
    else                 { in = Wp;  out = WpT;  R = 1024; C = 1024; bx = (wblk - 768) & 15; by = (wblk - 768) >> 4; }
    const int r0 = by << 6, c0 = bx << 6;
#pragma unroll
    for (int i = 0; i < 16; i++) {
        int idx = i * 256 + tid;
        int r = idx >> 6, c = idx & 63;
        t[r][c] = f2bf(in[(size_t)(r0 + r) * C + c0 + c]);
    }
    __syncthreads();
#pragma unroll
    for (int i = 0; i < 16; i++) {
        int idx = i * 256 + tid;
        int c = idx >> 6, r = idx & 63;
        out[(size_t)(c0 + c) * R + r0 + r] = t[r][c];
    }
}

// ---------------------------------------------------------------------------
// GEMM: C(MxN) = A(MxK) * B^T(NxK), bf16 in, fp32 acc. 128-tile, BK=64,
// 2-barrier structure. Used for the out-proj GEMM only.
// MFMA operands SWAPPED (acc transposed) -> column-packed vector stores.
// ---------------------------------------------------------------------------
template <bool OUTF32, int NT>
__global__ __launch_bounds__(256) void gemm_bt(const u16* __restrict__ A,
                                               const u16* __restrict__ B,
                                               void* __restrict__ Cv,
                                               const float* __restrict__ bias,
                                               int M, int N, int K) {
    constexpr int NJ = NT / 32;
    __shared__ __align__(16) u16 As[128 * 64];
    __shared__ __align__(16) u16 Bs[NT * 64];
    const int tid = threadIdx.x;
    const int wave = tid >> 6, lane = tid & 63;
    const int lrow = lane & 15, quad = lane >> 4;
    const int nb = N / NT;
    const int bx = blockIdx.x % nb, by = blockIdx.x / nb;
    const long m0 = (long)by << 7, n0 = (long)bx * NT;
    const int wm = (wave >> 1) << 6, wn = (wave & 1) * (NT / 2);

    const f32x4 fz = {0.f, 0.f, 0.f, 0.f};
    f32x4 acc[4][NJ];
#pragma unroll
    for (int i = 0; i < 4; i++)
#pragma unroll
        for (int j = 0; j < NJ; j++) acc[i][j] = fz;

    const int srow = wave * 8 + (lane >> 3);
    const int scol = ((lane & 7) ^ (lane >> 3)) << 3;
    const u16* Ag = A + (m0 + srow) * K + scol;
    const u16* Bg = B + (n0 + srow) * K + scol;
    u16* AsW = &As[wave * 512];
    u16* BsW = &Bs[wave * 512];

    for (int k0 = 0; k0 < K; k0 += 64) {
        __syncthreads();
#pragma unroll
        for (int c = 0; c < 4; c++)
            async16(Ag + (long)c * 32 * K + k0, AsW + c * 2048);
#pragma unroll
        for (int c = 0; c < NT / 32; c++)
            async16(Bg + (long)c * 32 * K + k0, BsW + c * 2048);
        __syncthreads();
#pragma unroll
        for (int c = 0; c < 2; c++) {
            bf16x8 af[4], bfr[NJ];
#pragma unroll
            for (int i = 0; i < 4; i++) {
                const int row = wm + i * 16 + lrow;
                af[i] = *(const bf16x8*)&As[row * 64 + (((c * 4 + quad) ^ (row & 7)) << 3)];
            }
#pragma unroll
            for (int j = 0; j < NJ; j++) {
                const int row = wn + j * 16 + lrow;
                bfr[j] = *(const bf16x8*)&Bs[row * 64 + (((c * 4 + quad) ^ (row & 7)) << 3)];
            }
#pragma unroll
            for (int i = 0; i < 4; i++)
#pragma unroll
                for (int j = 0; j < NJ; j++)
                    acc[i][j] = MFMA16(bfr[j], af[i], acc[i][j]);   // swapped
        }
    }
    // epilogue (transposed acc): row = m0+wm+i*16+lrow, cols = n0+wn+j*16+quad*4 .. +3
#pragma unroll
    for (int i = 0; i < 4; i++) {
        const long row = m0 + wm + i * 16 + lrow;
#pragma unroll
        for (int j = 0; j < NJ; j++) {
            const long colb = n0 + wn + j * 16 + quad * 4;
            if (OUTF32) {
                f32x4 v = acc[i][j];
                if (bias) v += *(const f32x4*)&bias[colb];
                *(f32x4*)&((float*)Cv)[row * N + colb] = v;
            } else {
                u16x4 pk;
#pragma unroll
                for (int r = 0; r < 4; r++) pk[r] = f2bf(acc[i][j][r]);
                *(u16x4*)&((u16*)Cv)[row * N + colb] = pk;
            }
        }
    }
}

// ---------------------------------------------------------------------------
// FUSED projection dispatch. Blocks [0,512): KV-projection GEMM, 256x256
// tile, 8 waves, counted-vmcnt 4-phase schedule with r6 direct epilogue
// (K half -> kvbuf interleaved, V half -> Vt transposed). Blocks [512,640):
// q-projection GEMM, 128x128 tile, 8 waves = two 4-wave teams sharing the
// As panel, 2-barrier gload_lds loop, swapped-operand epilogue.
// Fusing removes one launch gap and overlaps q-GEMM into kv's makespan.
// ---------------------------------------------------------------------------
__global__ __launch_bounds__(512, 2) void gemm_kv_q(const u16* __restrict__ A,
                                                    const u16* __restrict__ B,
                                                    u16* __restrict__ C,
                                                    u16* __restrict__ Vt,
                                                    const u16* __restrict__ Aq,
                                                    const u16* __restrict__ Wq,
                                                    u16* __restrict__ qbuf) {
    constexpr int K = 1024, N = 2048, NT = 16;  // NT = K/64 K-tiles
    __shared__ __align__(16) u16 As[2][256 * 64];
    __shared__ __align__(16) u16 Bs[2][256 * 64];
    const int tid = threadIdx.x;
    const int wave = tid >> 6, lane = tid & 63;
    const int lrow = lane & 15, quad = lane >> 4;
    const int p = blockIdx.x;
    const f32x4 fz = {0.f, 0.f, 0.f, 0.f};

    if (p >= 512) {
        // ---------------- q-projection path: tile 128x128 of C(2048x1024)
        const int p2 = p - 512;
        const int by = p2 >> 3, bxp = p2 & 7;
        const long m0 = (long)by << 7, n0 = (long)bxp << 7;
        constexpr int QN = 1024;
        u16* qAs = &As[0][0];                 // 128 x 64 = 8192 elems (16 KB)
        u16* qBs = &Bs[0][0];                 // 128 rows (two 64-row panels)
        const int team = wave >> 2, wv = wave & 3;
        const int wm = (wv >> 1) << 6, wn = (wv & 1) * 32;

        f32x4 acc[4][2];
#pragma unroll
        for (int i = 0; i < 4; i++)
#pragma unroll
            for (int j = 0; j < 2; j++) acc[i][j] = fz;

        const int srow = tid >> 3;            // 0..63
        const int scol = ((tid & 7) ^ (srow & 7)) << 3;
        const u16* Ag = Aq + (m0 + srow) * K + scol;
        const u16* Bg = Wq + (n0 + srow) * K + scol;

        for (int k0 = 0; k0 < K; k0 += 64) {
            __syncthreads();
#pragma unroll
            for (int c = 0; c < 2; c++)
                async16(Ag + (size_t)(c * 64) * K + k0, qAs + c * 4096 + tid * 8);
#pragma unroll
            for (int c = 0; c < 2; c++)
                async16(Bg + (size_t)(c * 64) * K + k0, qBs + c * 4096 + tid * 8);
            __syncthreads();
#pragma unroll
            for (int c = 0; c < 2; c++) {
                bf16x8 af[4], bfr[2];
#pragma unroll
                for (int i = 0; i < 4; i++) {
                    const int row = wm + i * 16 + lrow;
                    af[i] = *(const bf16x8*)&qAs[row * 64 + (((c * 4 + quad) ^ (row & 7)) << 3)];
                }
#pragma unroll
                for (int j = 0; j < 2; j++) {
                    const int row = team * 64 + wn + j * 16 + lrow;
                    bfr[j] = *(const bf16x8*)&qBs[row * 64 + (((c * 4 + quad) ^ (row & 7)) << 3)];
                }
#pragma unroll
                for (int i = 0; i < 4; i++)
#pragma unroll
                    for (int j = 0; j < 2; j++)
                        acc[i][j] = MFMA16(bfr[j], af[i], acc[i][j]);   // swapped
            }
        }
        // epilogue (transposed acc): row = m-dim (lane), cols packed along n
#pragma unroll
        for (int i = 0; i < 4; i++) {
            const long row = m0 + wm + i * 16 + lrow;
#pragma unroll
            for (int j = 0; j < 2; j++) {
                const long colb = n0 + team * 64 + wn + j * 16 + quad * 4;
                u16x4 pk;
#pragma unroll
                for (int r = 0; r < 4; r++) pk[r] = f2bf(acc[i][j][r]);
                *(u16x4*)&qbuf[row * QN + colb] = pk;
            }
        }
        return;
    }

    // ---------------- KV path (r6 frozen)
    const int wMi = wave >> 2, wNi = wave & 3;
    const int wm = wMi * 128, wn = wNi * 64;
    // bijective XCD swizzle: 512 wgs, 8 XCDs, 64 contiguous tiles each
    const int swz = (p & 7) * 64 + (p >> 3);
    const int bx = swz & 7, by = swz >> 3;
    const long m0 = (long)by << 8, n0 = (long)bx << 8;

    const int srow = tid >> 3;
    const int scol = ((tid & 7) ^ (srow & 7)) << 3;
    const u16* Ag = A + (m0 + srow) * K + scol;
    const u16* Bg = B + (n0 + srow) * K + scol;
    const int sdst = tid * 8;

    auto stgA = [&](int bi, int h, int kt) {
        async16(Ag + (size_t)(h * 128) * K + kt * 64,      &As[bi][h * 8192 + sdst]);
        async16(Ag + (size_t)(h * 128 + 64) * K + kt * 64, &As[bi][h * 8192 + 4096 + sdst]);
    };
    auto stgB = [&](int bi, int h, int kt) {
        async16(Bg + (size_t)(h * 128) * K + kt * 64,      &Bs[bi][h * 8192 + sdst]);
        async16(Bg + (size_t)(h * 128 + 64) * K + kt * 64, &Bs[bi][h * 8192 + 4096 + sdst]);
    };

    // prologue: t0{Blo,Bhi,Alo,Ahi}, t1{Blo,Bhi,Alo}; vmcnt(6) => t0 landed
    stgB(0, 0, 0); stgB(0, 1, 0); stgA(0, 0, 0); stgA(0, 1, 0);
    stgB(1, 0, 1); stgB(1, 1, 1); stgA(1, 0, 1);

    f32x4 acc[8][4];
#pragma unroll
    for (int i = 0; i < 8; i++)
#pragma unroll
        for (int j = 0; j < 4; j++) acc[i][j] = fz;

    asm volatile("s_waitcnt vmcnt(6)" ::: "memory");
    __builtin_amdgcn_s_barrier();

    bf16x8 av[4][2], bv[4][2];
    for (int t = 0; t < NT; ++t) {
        const int cur = t & 1, nxt = cur ^ 1;
        // ---- phase 1: ds_read A(i0-3) + B(all 8); stage (t+1).Ahi; MFMA i0-3 x j0-1
#pragma unroll
        for (int i = 0; i < 4; i++) {
            const int row = wm + i * 16 + lrow;
#pragma unroll
            for (int c = 0; c < 2; c++)
                av[i][c] = *(const bf16x8*)&As[cur][row * 64 + (((c * 4 + quad) ^ (row & 7)) << 3)];
        }
#pragma unroll
        for (int j = 0; j < 4; j++) {
            const int row = wn + j * 16 + lrow;
#pragma unroll
            for (int c = 0; c < 2; c++)
                bv[j][c] = *(const bf16x8*)&Bs[cur][row * 64 + (((c * 4 + quad) ^ (row & 7)) << 3)];
        }
        if (t + 1 < NT) stgA(nxt, 1, t + 1);
        __builtin_amdgcn_s_barrier();
        asm volatile("s_waitcnt lgkmcnt(0)" ::: "memory");
        __builtin_amdgcn_sched_barrier(0);
        __builtin_amdgcn_s_setprio(1);
#pragma unroll
        for (int i = 0; i < 4; i++)
#pragma unroll
            for (int j = 0; j < 2; j++)
#pragma unroll
                for (int c = 0; c < 2; c++)
                    acc[i][j] = MFMA16(av[i][c], bv[j][c], acc[i][j]);
        __builtin_amdgcn_s_setprio(0);
        __builtin_amdgcn_s_barrier();
        // ---- phase 2: stage (t+2).Blo; MFMA i0-3 x j2-3 (regs only)
        if (t + 2 < NT) stgB(cur, 0, t + 2);
        __builtin_amdgcn_s_barrier();
        __builtin_amdgcn_sched_barrier(0);
        __builtin_amdgcn_s_setprio(1);
#pragma unroll
        for (int i = 0; i < 4; i++)
#pragma unroll
            for (int j = 2; j < 4; j++)
#pragma unroll
                for (int c = 0; c < 2; c++)
                    acc[i][j] = MFMA16(av[i][c], bv[j][c], acc[i][j]);
        __builtin_amdgcn_s_setprio(0);
        __builtin_amdgcn_s_barrier();
        // ---- phase 3: ds_read A(i4-7); stage (t+2).Bhi; MFMA i4-7 x j0-1
#pragma unroll
        for (int i = 0; i < 4; i++) {
            const int row = wm + (i + 4) * 16 + lrow;
#pragma unroll
            for (int c = 0; c < 2; c++)
                av[i][c] = *(const bf16x8*)&As[cur][row * 64 + (((c * 4 + quad) ^ (row & 7)) << 3)];
        }
        if (t + 2 < NT) stgB(cur, 1, t + 2);
        __builtin_amdgcn_s_barrier();
        asm volatile("s_waitcnt lgkmcnt(0)" ::: "memory");
        __builtin_amdgcn_sched_barrier(0);
        __builtin_amdgcn_s_setprio(1);
#pragma unroll
        for (int i = 0; i < 4; i++)
#pragma unroll
            for (int j = 0; j < 2; j++)
#pragma unroll
                for (int c = 0; c < 2; c++)
                    acc[i + 4][j] = MFMA16(av[i][c], bv[j][c], acc[i + 4][j]);
        __builtin_amdgcn_s_setprio(0);
        __builtin_amdgcn_s_barrier();
        // ---- phase 4: stage (t+2).Alo; MFMA i4-7 x j2-3; counted vmcnt
        if (t + 2 < NT) stgA(cur, 0, t + 2);
        __builtin_amdgcn_s_barrier();
        __builtin_amdgcn_sched_barrier(0);
        __builtin_amdgcn_s_setprio(1);
#pragma unroll
        for (int i = 0; i < 4; i++)
#pragma unroll
            for (int j = 2; j < 4; j++)
#pragma unroll
                for (int c = 0; c < 2; c++)
                    acc[i + 4][j] = MFMA16(av[i][c], bv[j][c], acc[i + 4][j]);
        __builtin_amdgcn_s_setprio(0);
        if (t + 2 < NT)      { asm volatile("s_waitcnt vmcnt(6)" ::: "memory"); }
        else if (t + 1 < NT) { asm volatile("s_waitcnt vmcnt(0)" ::: "memory"); }
        __builtin_amdgcn_s_barrier();
    }

    // epilogue (r6). Tile = head bx: wNi<2 -> K half to kvbuf; wNi>=2 ->
    // V half transposed to Vt.
    const int h = bx;
    if (wNi < 2) {
#pragma unroll
        for (int j = 0; j < 4; j++) {
            const long col = n0 + wn + j * 16 + lrow;
#pragma unroll
            for (int i = 0; i < 8; i++) {
                const long row = m0 + wm + i * 16 + quad * 4;
#pragma unroll
                for (int r = 0; r < 4; r++)
                    C[(row + r) * N + col] = f2bf(acc[i][j][r]);
            }
        }
    } else {
#pragma unroll
        for (int j = 0; j < 4; j++) {
            const int dh = (wNi - 2) * 64 + j * 16 + lrow;
#pragma unroll
            for (int i = 0; i < 8; i++) {
                const int row = (int)m0 + wm + i * 16 + quad * 4;
                const int b = row >> 12, kv = row & 4095;
                u16x4 pk;
#pragma unroll
                for (int r = 0; r < 4; r++) pk[r] = f2bf(acc[i][j][r]);
                *(u16x4*)&Vt[(((size_t)b * 8 + h) * 128 + dh) * 4096 + kv] = pk;
            }
        }
    }
}

// ---------------------------------------------------------------------------
// Split-K flash attention (r6 best): kvbuf K reads, XCD chunking
// blk=(p&7)*64+(p>>3), double-buffered K/V LDS, T14 reg prefetch,
// 1 barrier/iter, defer-max, setprio. LDS 80 KiB -> 2 blocks/CU.
// ---------------------------------------------------------------------------
__global__ __launch_bounds__(512, 4) void flash_attn_split(const u16* __restrict__ qb,
                                                           const u16* __restrict__ kvb,
                                                           const u16* __restrict__ vTb,
                                                           float* __restrict__ Opart,
                                                           float* __restrict__ Mpart,
                                                           float* __restrict__ Lpart) {
    __shared__ __align__(16) u16 Ks[2][64 * 128];    // [kv][dh], blk^(kv&15) swizzle
    __shared__ __align__(16) u16 Vs[2][128 * 64];    // [dh][kv], blk^(dh&7) swizzle
    __shared__ __align__(16) u16 Ps[8][16 * 64];     // per-wave [q][kv]
    const int tid = threadIdx.x, wave = tid >> 6, lane = tid & 63;
    const int lrow = lane & 15, quad = lane >> 4;
    const int p = blockIdx.x;
    const int blk = (p & 7) * 64 + (p >> 3);         // logical id, XCD-chunked
    const int split = blk & 3, qt = (blk >> 2) & 3, h = (blk >> 4) & 7, b = blk >> 7;
    const int q0 = qt * 128;
    const int kbase = split * 1024;

    bf16x8 qf[4];
    {
        const u16* qp = qb + (((size_t)(b * 512 + q0 + wave * 16 + lrow) * 8 + h) << 7) + quad * 8;
#pragma unroll
        for (int c = 0; c < 4; c++) qf[c] = *(const bf16x8*)(qp + c * 32);
    }

    const f32x4 fz = {0.f, 0.f, 0.f, 0.f};
    f32x4 oacc[8];
#pragma unroll
    for (int g = 0; g < 8; g++) oacc[g] = fz;
    float mrow = -1e30f, lsum = 0.f;
    const float scale = 0.08838834764831845f;

    const int kRow = tid >> 4, kBlk = tid & 15;   // K: rows kRow, kRow+32
    const int vRow = tid >> 3, vBlk = tid & 7;    // V: rows vRow, vRow+64
    const u16* kg = kvb + (size_t)b * 4096 * 2048 + h * 256 + kBlk * 8;
    const u16* vg = vTb + (size_t)(b * 8 + h) * 128 * 4096 + vBlk * 8;
    const int ksw = (kBlk ^ (kRow & 15)) << 3;    // same swizzle for row kRow+32
    const int vsw = (vBlk ^ (vRow & 7)) << 3;     // same swizzle for row vRow+64

    // prologue: stage tile 0 into buf 0
    {
        const bf16x8 a0 = *(const bf16x8*)&kg[(size_t)(kbase + kRow) * 2048];
        const bf16x8 a1 = *(const bf16x8*)&kg[(size_t)(kbase + 32 + kRow) * 2048];
        const bf16x8 b0 = *(const bf16x8*)&vg[(size_t)vRow * 4096 + kbase];
        const bf16x8 b1 = *(const bf16x8*)&vg[(size_t)(64 + vRow) * 4096 + kbase];
        *(bf16x8*)&Ks[0][kRow * 128 + ksw] = a0;
        *(bf16x8*)&Ks[0][(32 + kRow) * 128 + ksw] = a1;
        *(bf16x8*)&Vs[0][vRow * 64 + vsw] = b0;
        *(bf16x8*)&Vs[0][(64 + vRow) * 64 + vsw] = b1;
    }
    __syncthreads();

    for (int it = 0; it < 16; ++it) {
        const int cur = it & 1, nxt = cur ^ 1;
        const bool more = (it + 1 < 16);
        // T14: issue next-tile loads early; latency hides under QK+softmax+PV
        bf16x8 nk0, nk1, nv0, nv1;
        if (more) {
            const int k1 = kbase + (it + 1) * 64;
            nk0 = *(const bf16x8*)&kg[(size_t)(k1 + kRow) * 2048];
            nk1 = *(const bf16x8*)&kg[(size_t)(k1 + 32 + kRow) * 2048];
            nv0 = *(const bf16x8*)&vg[(size_t)vRow * 4096 + k1];
            nv1 = *(const bf16x8*)&vg[(size_t)(64 + vRow) * 4096 + k1];
        }

        // QK^T on Ks[cur]
        f32x4 s[4];
        __builtin_amdgcn_s_setprio(1);
#pragma unroll
        for (int t = 0; t < 4; t++) {
            f32x4 a = fz;
#pragma unroll
            for (int c = 0; c < 4; c++) {
                const bf16x8 kf = *(const bf16x8*)
                    &Ks[cur][(t * 16 + lrow) * 128 + (((c * 4 + quad) ^ lrow) << 3)];
                a = MFMA16(kf, qf[c], a);
            }
            s[t] = a * scale;
        }
        __builtin_amdgcn_s_setprio(0);

        // online softmax with defer-max (T13, THR=8)
        float mx = s[0][0];
#pragma unroll
        for (int t = 0; t < 4; t++)
#pragma unroll
            for (int r = 0; r < 4; r++) mx = fmaxf(mx, s[t][r]);
        mx = fmaxf(mx, __shfl_xor(mx, 16));
        mx = fmaxf(mx, __shfl_xor(mx, 32));
        float mn = fmaxf(mrow, mx);
        if (__all(mx <= mrow + 8.f)) {
            mn = mrow;                       // defer: keep old max, no rescale
        } else {
            const float alpha = __expf(mrow - mn);
#pragma unroll
            for (int g = 0; g < 8; g++) oacc[g] *= alpha;
            lsum *= alpha;
            mrow = mn;
        }
        float sum = 0.f;
#pragma unroll
        for (int t = 0; t < 4; t++)
#pragma unroll
            for (int r = 0; r < 4; r++) {
                float pv = __expf(s[t][r] - mn);
                s[t][r] = pv;
                sum += pv;
            }
        sum += __shfl_xor(sum, 16);
        sum += __shfl_xor(sum, 32);
        lsum += sum;

        // P pack -> per-wave LDS, then PV on Vs[cur]
        u16* Pw = &Ps[wave][0];
#pragma unroll
        for (int t = 0; t < 4; t++) {
            u16x4 pk;
#pragma unroll
            for (int r = 0; r < 4; r++) pk[r] = f2bf(s[t][r]);
            const int kvo = t * 16 + quad * 4;
            *(u16x4*)&Pw[lrow * 64 + (((kvo >> 3) ^ (lrow & 7)) << 3) + (kvo & 7)] = pk;
        }
        asm volatile("s_waitcnt lgkmcnt(0)" ::: "memory");
        __builtin_amdgcn_sched_barrier(0);
        const bf16x8 pf0 = *(const bf16x8*)&Pw[lrow * 64 + ((quad ^ (lrow & 7)) << 3)];
        const bf16x8 pf1 = *(const bf16x8*)&Pw[lrow * 64 + (((4 + quad) ^ (lrow & 7)) << 3)];

        __builtin_amdgcn_s_setprio(1);
#pragma unroll
        for (int g = 0; g < 8; g++) {
            f32x4 o = oacc[g];
            o = MFMA16(*(const bf16x8*)&Vs[cur][(g * 16 + lrow) * 64 + ((quad ^ (lrow & 7)) << 3)], pf0, o);
            o = MFMA16(*(const bf16x8*)&Vs[cur][(g * 16 + lrow) * 64 + (((4 + quad) ^ (lrow & 7)) << 3)], pf1, o);
            oacc[g] = o;
        }
        __builtin_amdgcn_s_setprio(0);

        // write next tile into the other buffer (its readers finished before
        // the previous iteration's barrier)
        if (more) {
            *(bf16x8*)&Ks[nxt][kRow * 128 + ksw] = nk0;
            *(bf16x8*)&Ks[nxt][(32 + kRow) * 128 + ksw] = nk1;
            *(bf16x8*)&Vs[nxt][vRow * 64 + vsw] = nv0;
            *(bf16x8*)&Vs[nxt][(64 + vRow) * 64 + vsw] = nv1;
        }
        __syncthreads();
    }

    // unnormalized partials: Ob[q*128 + dh] (indexed by LOGICAL blk)
    float* Ob = Opart + (size_t)blk * 16384;
#pragma unroll
    for (int g = 0; g < 8; g++)
        *(f32x4*)&Ob[(wave * 16 + lrow) * 128 + g * 16 + quad * 4] = oacc[g];
    if (quad == 0) {
        const int row = blk * 128 + wave * 16 + lrow;
        Mpart[row] = mrow;
        Lpart[row] = lsum;
    }
}

// ---------------------------------------------------------------------------
// Combine 4 split partials -> obuf (B,Q,H,128) bf16.
// grid 128 (= (b*8+h)*4+qt), 512 threads: 128 rows x 4 col-groups of 32.
// ---------------------------------------------------------------------------
__global__ __launch_bounds__(512) void combine_attn(const float* __restrict__ Opart,
                                                    const float* __restrict__ Mpart,
                                                    const float* __restrict__ Lpart,
                                                    u16* __restrict__ ob) {
    const int c = blockIdx.x;
    const int qt = c & 3, h = (c >> 2) & 7, b = c >> 5;
    const int lr = threadIdx.x >> 2, cg = (threadIdx.x & 3) * 32;
    float ms[4], w[4];
    float m = -1e30f;
#pragma unroll
    for (int s = 0; s < 4; s++) { ms[s] = Mpart[(c * 4 + s) * 128 + lr]; m = fmaxf(m, ms[s]); }
    float l = 0.f;
#pragma unroll
    for (int s = 0; s < 4; s++) { w[s] = __expf(ms[s] - m); l += w[s] * Lpart[(c * 4 + s) * 128 + lr]; }
    const float inv = 1.f / l;
#pragma unroll
    for (int s = 0; s < 4; s++) w[s] *= inv;
    const size_t orow = ((size_t)(b * 512 + qt * 128 + lr) * 8 + h) << 7;
#pragma unroll
    for (int j = 0; j < 4; j++) {
        f32x4 a0 = {0.f, 0.f, 0.f, 0.f}, a1 = a0;
#pragma unroll
        for (int s = 0; s < 4; s++) {
            const f32x4* pp = (const f32x4*)(Opart + ((size_t)(c * 4 + s)) * 16384 + (size_t)lr * 128 + cg + j * 8);
            a0 += pp[0] * w[s];
            a1 += pp[1] * w[s];
        }
        u16x8 v;
#pragma unroll
        for (int i = 0; i < 4; i++) { v[i] = f2bf(a0[i]); v[4 + i] = f2bf(a1[i]); }
        *(u16x8*)&ob[orow + cg + j * 8] = v;
    }
}

// ---------------------------------------------------------------------------
extern "C" void kernel_launch(void* const* d_in, const int* in_sizes, int n_in,
                              void* d_out, int out_size, void* d_ws, size_t ws_size,
                              hipStream_t stream) {
    const float* inq   = (const float*)d_in[0];
    const float* inkv  = (const float*)d_in[1];
    const float* Wq    = (const float*)d_in[2];
    const float* Wkv   = (const float*)d_in[3];
    const float* Wproj = (const float*)d_in[4];
    const float* bproj = (const float*)d_in[5];
    float* out = (float*)d_out;

    u16* WqT    = (u16*)d_ws;                          // 1M elems
    u16* WkvT   = WqT + (size_t)1024 * 1024;           // 2M
    u16* WprojT = WkvT + (size_t)2048 * 1024;          // 1M
    u16* Aq     = WprojT + (size_t)1024 * 1024;        // 2M   bf16(inputs_q)
    u16* Akv    = Aq + (size_t)2048 * 1024;            // 16M  bf16(inputs_kv); dead after kv-gemm
    u16* qbuf   = Akv + (size_t)16384 * 1024;          // 2M   (B,Q,H,DH)
    u16* kvbuf  = qbuf + (size_t)2048 * 1024;          // 32M  (B,K,H,2DH) K-half valid
    u16* vTbuf  = kvbuf + (size_t)16384 * 2048;        // 16M  (B,H,DH,K)
    u16* obuf   = vTbuf + (size_t)32 * 128 * 4096;     // 2M   (B,Q,H,DH)

    float* Opart = (float*)Akv;                        // 512*16384 f32 = 32 MB
    float* Mpart = (float*)Aq;                         // 64K f32
    float* Lpart = Mpart + 65536;                      // 64K f32

    prep_all<<<10240, 256, 0, stream>>>(inq, Aq, inkv, Akv, Wq, WqT, Wkv, WkvT, Wproj, WprojT);

    gemm_kv_q<<<640, 512, 0, stream>>>(Akv, WkvT, kvbuf, vTbuf, Aq, WqT, qbuf);

    flash_attn_split<<<512, 512, 0, stream>>>(qbuf, kvbuf, vTbuf, Opart, Mpart, Lpart);
    combine_attn<<<128, 512, 0, stream>>>(Opart, Mpart, Lpart, obuf);

    gemm_bt<true, 64><<<16 * 16, 256, 0, stream>>>(obuf, WprojT, (void*)out, bproj, 2048, 1024, 1024);
}

// Round 11
// 295.628 us; speedup vs baseline: 1.0582x; 1.0209x over previous
//
#include <hip/hip_runtime.h>
#include <hip/hip_bf16.h>
#include <cstdint>

typedef unsigned short u16;
typedef unsigned int u32;
typedef __bf16 bf16x8 __attribute__((ext_vector_type(8)));
typedef u16 u16x8 __attribute__((ext_vector_type(8)));
typedef u16 u16x4 __attribute__((ext_vector_type(4)));
typedef float f32x4 __attribute__((ext_vector_type(4)));

#define MFMA16(a, b, c) __builtin_amdgcn_mfma_f32_16x16x32_bf16(a, b, c, 0, 0, 0)

__device__ __forceinline__ void async16(const void* g, void* s) {
    __builtin_amdgcn_global_load_lds((const __attribute__((address_space(1))) void*)g,
                                     (__attribute__((address_space(3))) void*)s, 16, 0, 0);
}

__device__ __forceinline__ u16 f2bf(float f) {
    u32 u; __builtin_memcpy(&u, &f, 4);
    u = u + 0x7fffu + ((u >> 16) & 1u);
    return (u16)(u >> 16);
}

// ---------------------------------------------------------------------------
// Fused prep: blocks [0,9216) = input converts (f32->bf16, 8/thread);
// blocks [9216,10240) = weight transpose-converts. One dispatch.
// ---------------------------------------------------------------------------
__global__ __launch_bounds__(256) void prep_all(const float* __restrict__ inq,
                                                u16* __restrict__ Aq,
                                                const float* __restrict__ inkv,
                                                u16* __restrict__ Akv,
                                                const float* __restrict__ Wq,  u16* __restrict__ WqT,
                                                const float* __restrict__ Wkv, u16* __restrict__ WkvT,
                                                const float* __restrict__ Wp,  u16* __restrict__ WpT) {
    __shared__ u16 t[64][65];
    const int blk = blockIdx.x;
    const int tid = threadIdx.x;
    if (blk < 9216) {
        const float* in; u16* out; size_t i;
        if (blk < 1024) { in = inq;  out = Aq;  i = (size_t)blk * 256 + tid; }
        else            { in = inkv; out = Akv; i = (size_t)(blk - 1024) * 256 + tid; }
        const float4* p = (const float4*)in + i * 2;
        const float4 a = p[0], b = p[1];
        u16x8 v;
        v[0] = f2bf(a.x); v[1] = f2bf(a.y); v[2] = f2bf(a.z); v[3] = f2bf(a.w);
        v[4] = f2bf(b.x); v[5] = f2bf(b.y); v[6] = f2bf(b.z); v[7] = f2bf(b.w);
        ((u16x8*)out)[i] = v;
        return;
    }
    const int wblk = blk - 9216;
    const float* in; u16* out; int R, C, bx, by;
    if (wblk < 256)      { in = Wq;  out = WqT;  R = 1024; C = 1024; bx = wblk & 15;  by = wblk >> 4; }
    else if (wblk < 768) { in = Wkv; out = WkvT; R = 1024; C = 2048; bx = (wblk - 256) & 31; by = (wblk - 256) >> 5; }
    else                 { in = Wp;  out = WpT;  R = 1024; C = 1024; bx = (wblk - 768) & 15; by = (wblk - 768) >> 4; }
    const int r0 = by << 6, c0 = bx << 6;
#pragma unroll
    for (int i = 0; i < 16; i++) {
        int idx = i * 256 + tid;
        int r = idx >> 6, c = idx & 63;
        t[r][c] = f2bf(in[(size_t)(r0 + r) * C + c0 + c]);
    }
    __syncthreads();
#pragma unroll
    for (int i = 0; i < 16; i++) {
        int idx = i * 256 + tid;
        int c = idx >> 6, r = idx & 63;
        out[(size_t)(c0 + c) * R + r0 + r] = t[r][c];
    }
}

// ---------------------------------------------------------------------------
// GEMM: C(MxN) = A(MxK) * B^T(NxK), bf16 in, fp32 acc. 128-tile, BK=64,
// 2-barrier structure. Used for the small q / out-proj GEMMs only.
// MFMA operands SWAPPED (acc transposed) -> column-packed vector stores.
// ---------------------------------------------------------------------------
template <bool OUTF32, int NT>
__global__ __launch_bounds__(256) void gemm_bt(const u16* __restrict__ A,
                                               const u16* __restrict__ B,
                                               void* __restrict__ Cv,
                                               const float* __restrict__ bias,
                                               int M, int N, int K) {
    constexpr int NJ = NT / 32;
    __shared__ __align__(16) u16 As[128 * 64];
    __shared__ __align__(16) u16 Bs[NT * 64];
    const int tid = threadIdx.x;
    const int wave = tid >> 6, lane = tid & 63;
    const int lrow = lane & 15, quad = lane >> 4;
    const int nb = N / NT;
    const int bx = blockIdx.x % nb, by = blockIdx.x / nb;
    const long m0 = (long)by << 7, n0 = (long)bx * NT;
    const int wm = (wave >> 1) << 6, wn = (wave & 1) * (NT / 2);

    const f32x4 fz = {0.f, 0.f, 0.f, 0.f};
    f32x4 acc[4][NJ];
#pragma unroll
    for (int i = 0; i < 4; i++)
#pragma unroll
        for (int j = 0; j < NJ; j++) acc[i][j] = fz;

    const int srow = wave * 8 + (lane >> 3);
    const int scol = ((lane & 7) ^ (lane >> 3)) << 3;
    const u16* Ag = A + (m0 + srow) * K + scol;
    const u16* Bg = B + (n0 + srow) * K + scol;
    u16* AsW = &As[wave * 512];
    u16* BsW = &Bs[wave * 512];

    for (int k0 = 0; k0 < K; k0 += 64) {
        __syncthreads();
#pragma unroll
        for (int c = 0; c < 4; c++)
            async16(Ag + (long)c * 32 * K + k0, AsW + c * 2048);
#pragma unroll
        for (int c = 0; c < NT / 32; c++)
            async16(Bg + (long)c * 32 * K + k0, BsW + c * 2048);
        __syncthreads();
#pragma unroll
        for (int c = 0; c < 2; c++) {
            bf16x8 af[4], bfr[NJ];
#pragma unroll
            for (int i = 0; i < 4; i++) {
                const int row = wm + i * 16 + lrow;
                af[i] = *(const bf16x8*)&As[row * 64 + (((c * 4 + quad) ^ (row & 7)) << 3)];
            }
#pragma unroll
            for (int j = 0; j < NJ; j++) {
                const int row = wn + j * 16 + lrow;
                bfr[j] = *(const bf16x8*)&Bs[row * 64 + (((c * 4 + quad) ^ (row & 7)) << 3)];
            }
#pragma unroll
            for (int i = 0; i < 4; i++)
#pragma unroll
                for (int j = 0; j < NJ; j++)
                    acc[i][j] = MFMA16(bfr[j], af[i], acc[i][j]);   // swapped
        }
    }
    // epilogue (transposed acc): row = m0+wm+i*16+lrow, cols = n0+wn+j*16+quad*4 .. +3
#pragma unroll
    for (int i = 0; i < 4; i++) {
        const long row = m0 + wm + i * 16 + lrow;
#pragma unroll
        for (int j = 0; j < NJ; j++) {
            const long colb = n0 + wn + j * 16 + quad * 4;
            if (OUTF32) {
                f32x4 v = acc[i][j];
                if (bias) v += *(const f32x4*)&bias[colb];
                *(f32x4*)&((float*)Cv)[row * N + colb] = v;
            } else {
                u16x4 pk;
#pragma unroll
                for (int r = 0; r < 4; r++) pk[r] = f2bf(acc[i][j][r]);
                *(u16x4*)&((u16*)Cv)[row * N + colb] = pk;
            }
        }
    }
}

// ---------------------------------------------------------------------------
// KV-projection GEMM, 256x256 tile, 8 waves, counted-vmcnt 4-phase schedule
// (frozen at r6 best-measured). Epilogue: K half -> kvbuf interleaved,
// V half -> Vt transposed.
// ---------------------------------------------------------------------------
__global__ __launch_bounds__(512, 2) void gemm_kv256(const u16* __restrict__ A,
                                                     const u16* __restrict__ B,
                                                     u16* __restrict__ C,
                                                     u16* __restrict__ Vt) {
    constexpr int K = 1024, N = 2048, NT = 16;  // NT = K/64 K-tiles
    __shared__ __align__(16) u16 As[2][256 * 64];
    __shared__ __align__(16) u16 Bs[2][256 * 64];
    const int tid = threadIdx.x;
    const int wave = tid >> 6, lane = tid & 63;
    const int lrow = lane & 15, quad = lane >> 4;
    const int wMi = wave >> 2, wNi = wave & 3;
    const int wm = wMi * 128, wn = wNi * 64;
    // bijective XCD swizzle: 512 wgs, 8 XCDs, 64 contiguous tiles each
    const int wg = blockIdx.x;
    const int swz = (wg & 7) * 64 + (wg >> 3);
    const int bx = swz & 7, by = swz >> 3;
    const long m0 = (long)by << 8, n0 = (long)bx << 8;

    const int srow = tid >> 3;
    const int scol = ((tid & 7) ^ (srow & 7)) << 3;
    const u16* Ag = A + (m0 + srow) * K + scol;
    const u16* Bg = B + (n0 + srow) * K + scol;
    const int sdst = tid * 8;

    auto stgA = [&](int bi, int h, int kt) {
        async16(Ag + (size_t)(h * 128) * K + kt * 64,      &As[bi][h * 8192 + sdst]);
        async16(Ag + (size_t)(h * 128 + 64) * K + kt * 64, &As[bi][h * 8192 + 4096 + sdst]);
    };
    auto stgB = [&](int bi, int h, int kt) {
        async16(Bg + (size_t)(h * 128) * K + kt * 64,      &Bs[bi][h * 8192 + sdst]);
        async16(Bg + (size_t)(h * 128 + 64) * K + kt * 64, &Bs[bi][h * 8192 + 4096 + sdst]);
    };

    // prologue: t0{Blo,Bhi,Alo,Ahi}, t1{Blo,Bhi,Alo}; vmcnt(6) => t0 landed
    stgB(0, 0, 0); stgB(0, 1, 0); stgA(0, 0, 0); stgA(0, 1, 0);
    stgB(1, 0, 1); stgB(1, 1, 1); stgA(1, 0, 1);

    const f32x4 fz = {0.f, 0.f, 0.f, 0.f};
    f32x4 acc[8][4];
#pragma unroll
    for (int i = 0; i < 8; i++)
#pragma unroll
        for (int j = 0; j < 4; j++) acc[i][j] = fz;

    asm volatile("s_waitcnt vmcnt(6)" ::: "memory");
    __builtin_amdgcn_s_barrier();

    bf16x8 av[4][2], bv[4][2];
    for (int t = 0; t < NT; ++t) {
        const int cur = t & 1, nxt = cur ^ 1;
        // ---- phase 1: ds_read A(i0-3) + B(all 8); stage (t+1).Ahi; MFMA i0-3 x j0-1
#pragma unroll
        for (int i = 0; i < 4; i++) {
            const int row = wm + i * 16 + lrow;
#pragma unroll
            for (int c = 0; c < 2; c++)
                av[i][c] = *(const bf16x8*)&As[cur][row * 64 + (((c * 4 + quad) ^ (row & 7)) << 3)];
        }
#pragma unroll
        for (int j = 0; j < 4; j++) {
            const int row = wn + j * 16 + lrow;
#pragma unroll
            for (int c = 0; c < 2; c++)
                bv[j][c] = *(const bf16x8*)&Bs[cur][row * 64 + (((c * 4 + quad) ^ (row & 7)) << 3)];
        }
        if (t + 1 < NT) stgA(nxt, 1, t + 1);
        __builtin_amdgcn_s_barrier();
        asm volatile("s_waitcnt lgkmcnt(0)" ::: "memory");
        __builtin_amdgcn_sched_barrier(0);
        __builtin_amdgcn_s_setprio(1);
#pragma unroll
        for (int i = 0; i < 4; i++)
#pragma unroll
            for (int j = 0; j < 2; j++)
#pragma unroll
                for (int c = 0; c < 2; c++)
                    acc[i][j] = MFMA16(av[i][c], bv[j][c], acc[i][j]);
        __builtin_amdgcn_s_setprio(0);
        __builtin_amdgcn_s_barrier();
        // ---- phase 2: stage (t+2).Blo; MFMA i0-3 x j2-3 (regs only)
        if (t + 2 < NT) stgB(cur, 0, t + 2);
        __builtin_amdgcn_s_barrier();
        __builtin_amdgcn_sched_barrier(0);
        __builtin_amdgcn_s_setprio(1);
#pragma unroll
        for (int i = 0; i < 4; i++)
#pragma unroll
            for (int j = 2; j < 4; j++)
#pragma unroll
                for (int c = 0; c < 2; c++)
                    acc[i][j] = MFMA16(av[i][c], bv[j][c], acc[i][j]);
        __builtin_amdgcn_s_setprio(0);
        __builtin_amdgcn_s_barrier();
        // ---- phase 3: ds_read A(i4-7); stage (t+2).Bhi; MFMA i4-7 x j0-1
#pragma unroll
        for (int i = 0; i < 4; i++) {
            const int row = wm + (i + 4) * 16 + lrow;
#pragma unroll
            for (int c = 0; c < 2; c++)
                av[i][c] = *(const bf16x8*)&As[cur][row * 64 + (((c * 4 + quad) ^ (row & 7)) << 3)];
        }
        if (t + 2 < NT) stgB(cur, 1, t + 2);
        __builtin_amdgcn_s_barrier();
        asm volatile("s_waitcnt lgkmcnt(0)" ::: "memory");
        __builtin_amdgcn_sched_barrier(0);
        __builtin_amdgcn_s_setprio(1);
#pragma unroll
        for (int i = 0; i < 4; i++)
#pragma unroll
            for (int j = 0; j < 2; j++)
#pragma unroll
                for (int c = 0; c < 2; c++)
                    acc[i + 4][j] = MFMA16(av[i][c], bv[j][c], acc[i + 4][j]);
        __builtin_amdgcn_s_setprio(0);
        __builtin_amdgcn_s_barrier();
        // ---- phase 4: stage (t+2).Alo; MFMA i4-7 x j2-3; counted vmcnt
        if (t + 2 < NT) stgA(cur, 0, t + 2);
        __builtin_amdgcn_s_barrier();
        __builtin_amdgcn_sched_barrier(0);
        __builtin_amdgcn_s_setprio(1);
#pragma unroll
        for (int i = 0; i < 4; i++)
#pragma unroll
            for (int j = 2; j < 4; j++)
#pragma unroll
                for (int c = 0; c < 2; c++)
                    acc[i + 4][j] = MFMA16(av[i][c], bv[j][c], acc[i + 4][j]);
        __builtin_amdgcn_s_setprio(0);
        if (t + 2 < NT)      { asm volatile("s_waitcnt vmcnt(6)" ::: "memory"); }
        else if (t + 1 < NT) { asm volatile("s_waitcnt vmcnt(0)" ::: "memory"); }
        __builtin_amdgcn_s_barrier();
    }

    // epilogue (r6). Tile = head bx: wNi<2 -> K half to kvbuf; wNi>=2 ->
    // V half transposed to Vt.
    const int h = bx;
    if (wNi < 2) {
#pragma unroll
        for (int j = 0; j < 4; j++) {
            const long col = n0 + wn + j * 16 + lrow;
#pragma unroll
            for (int i = 0; i < 8; i++) {
                const long row = m0 + wm + i * 16 + quad * 4;
#pragma unroll
                for (int r = 0; r < 4; r++)
                    C[(row + r) * N + col] = f2bf(acc[i][j][r]);
            }
        }
    } else {
#pragma unroll
        for (int j = 0; j < 4; j++) {
            const int dh = (wNi - 2) * 64 + j * 16 + lrow;
#pragma unroll
            for (int i = 0; i < 8; i++) {
                const int row = (int)m0 + wm + i * 16 + quad * 4;
                const int b = row >> 12, kv = row & 4095;
                u16x4 pk;
#pragma unroll
                for (int r = 0; r < 4; r++) pk[r] = f2bf(acc[i][j][r]);
                *(u16x4*)&Vt[(((size_t)b * 8 + h) * 128 + dh) * 4096 + kv] = pk;
            }
        }
    }
}

// ---------------------------------------------------------------------------
// Split-K flash attention (r6 best): kvbuf K reads, XCD chunking
// blk=(p&7)*64+(p>>3), double-buffered K/V LDS, T14 reg prefetch,
// 1 barrier/iter, defer-max, setprio. LDS 80 KiB -> 2 blocks/CU.
// ---------------------------------------------------------------------------
__global__ __launch_bounds__(512, 4) void flash_attn_split(const u16* __restrict__ qb,
                                                           const u16* __restrict__ kvb,
                                                           const u16* __restrict__ vTb,
                                                           float* __restrict__ Opart,
                                                           float* __restrict__ Mpart,
                                                           float* __restrict__ Lpart) {
    __shared__ __align__(16) u16 Ks[2][64 * 128];    // [kv][dh], blk^(kv&15) swizzle
    __shared__ __align__(16) u16 Vs[2][128 * 64];    // [dh][kv], blk^(dh&7) swizzle
    __shared__ __align__(16) u16 Ps[8][16 * 64];     // per-wave [q][kv]
    const int tid = threadIdx.x, wave = tid >> 6, lane = tid & 63;
    const int lrow = lane & 15, quad = lane >> 4;
    const int p = blockIdx.x;
    const int blk = (p & 7) * 64 + (p >> 3);         // logical id, XCD-chunked
    const int split = blk & 3, qt = (blk >> 2) & 3, h = (blk >> 4) & 7, b = blk >> 7;
    const int q0 = qt * 128;
    const int kbase = split * 1024;

    bf16x8 qf[4];
    {
        const u16* qp = qb + (((size_t)(b * 512 + q0 + wave * 16 + lrow) * 8 + h) << 7) + quad * 8;
#pragma unroll
        for (int c = 0; c < 4; c++) qf[c] = *(const bf16x8*)(qp + c * 32);
    }

    const f32x4 fz = {0.f, 0.f, 0.f, 0.f};
    f32x4 oacc[8];
#pragma unroll
    for (int g = 0; g < 8; g++) oacc[g] = fz;
    float mrow = -1e30f, lsum = 0.f;
    const float scale = 0.08838834764831845f;

    const int kRow = tid >> 4, kBlk = tid & 15;   // K: rows kRow, kRow+32
    const int vRow = tid >> 3, vBlk = tid & 7;    // V: rows vRow, vRow+64
    const u16* kg = kvb + (size_t)b * 4096 * 2048 + h * 256 + kBlk * 8;
    const u16* vg = vTb + (size_t)(b * 8 + h) * 128 * 4096 + vBlk * 8;
    const int ksw = (kBlk ^ (kRow & 15)) << 3;    // same swizzle for row kRow+32
    const int vsw = (vBlk ^ (vRow & 7)) << 3;     // same swizzle for row vRow+64

    // prologue: stage tile 0 into buf 0
    {
        const bf16x8 a0 = *(const bf16x8*)&kg[(size_t)(kbase + kRow) * 2048];
        const bf16x8 a1 = *(const bf16x8*)&kg[(size_t)(kbase + 32 + kRow) * 2048];
        const bf16x8 b0 = *(const bf16x8*)&vg[(size_t)vRow * 4096 + kbase];
        const bf16x8 b1 = *(const bf16x8*)&vg[(size_t)(64 + vRow) * 4096 + kbase];
        *(bf16x8*)&Ks[0][kRow * 128 + ksw] = a0;
        *(bf16x8*)&Ks[0][(32 + kRow) * 128 + ksw] = a1;
        *(bf16x8*)&Vs[0][vRow * 64 + vsw] = b0;
        *(bf16x8*)&Vs[0][(64 + vRow) * 64 + vsw] = b1;
    }
    __syncthreads();

    for (int it = 0; it < 16; ++it) {
        const int cur = it & 1, nxt = cur ^ 1;
        const bool more = (it + 1 < 16);
        // T14: issue next-tile loads early; latency hides under QK+softmax+PV
        bf16x8 nk0, nk1, nv0, nv1;
        if (more) {
            const int k1 = kbase + (it + 1) * 64;
            nk0 = *(const bf16x8*)&kg[(size_t)(k1 + kRow) * 2048];
            nk1 = *(const bf16x8*)&kg[(size_t)(k1 + 32 + kRow) * 2048];
            nv0 = *(const bf16x8*)&vg[(size_t)vRow * 4096 + k1];
            nv1 = *(const bf16x8*)&vg[(size_t)(64 + vRow) * 4096 + k1];
        }

        // QK^T on Ks[cur]
        f32x4 s[4];
        __builtin_amdgcn_s_setprio(1);
#pragma unroll
        for (int t = 0; t < 4; t++) {
            f32x4 a = fz;
#pragma unroll
            for (int c = 0; c < 4; c++) {
                const bf16x8 kf = *(const bf16x8*)
                    &Ks[cur][(t * 16 + lrow) * 128 + (((c * 4 + quad) ^ lrow) << 3)];
                a = MFMA16(kf, qf[c], a);
            }
            s[t] = a * scale;
        }
        __builtin_amdgcn_s_setprio(0);

        // online softmax with defer-max (T13, THR=8)
        float mx = s[0][0];
#pragma unroll
        for (int t = 0; t < 4; t++)
#pragma unroll
            for (int r = 0; r < 4; r++) mx = fmaxf(mx, s[t][r]);
        mx = fmaxf(mx, __shfl_xor(mx, 16));
        mx = fmaxf(mx, __shfl_xor(mx, 32));
        float mn = fmaxf(mrow, mx);
        if (__all(mx <= mrow + 8.f)) {
            mn = mrow;                       // defer: keep old max, no rescale
        } else {
            const float alpha = __expf(mrow - mn);
#pragma unroll
            for (int g = 0; g < 8; g++) oacc[g] *= alpha;
            lsum *= alpha;
            mrow = mn;
        }
        float sum = 0.f;
#pragma unroll
        for (int t = 0; t < 4; t++)
#pragma unroll
            for (int r = 0; r < 4; r++) {
                float pv = __expf(s[t][r] - mn);
                s[t][r] = pv;
                sum += pv;
            }
        sum += __shfl_xor(sum, 16);
        sum += __shfl_xor(sum, 32);
        lsum += sum;

        // P pack -> per-wave LDS, then PV on Vs[cur]
        u16* Pw = &Ps[wave][0];
#pragma unroll
        for (int t = 0; t < 4; t++) {
            u16x4 pk;
#pragma unroll
            for (int r = 0; r < 4; r++) pk[r] = f2bf(s[t][r]);
            const int kvo = t * 16 + quad * 4;
            *(u16x4*)&Pw[lrow * 64 + (((kvo >> 3) ^ (lrow & 7)) << 3) + (kvo & 7)] = pk;
        }
        asm volatile("s_waitcnt lgkmcnt(0)" ::: "memory");
        __builtin_amdgcn_sched_barrier(0);
        const bf16x8 pf0 = *(const bf16x8*)&Pw[lrow * 64 + ((quad ^ (lrow & 7)) << 3)];
        const bf16x8 pf1 = *(const bf16x8*)&Pw[lrow * 64 + (((4 + quad) ^ (lrow & 7)) << 3)];

        __builtin_amdgcn_s_setprio(1);
#pragma unroll
        for (int g = 0; g < 8; g++) {
            f32x4 o = oacc[g];
            o = MFMA16(*(const bf16x8*)&Vs[cur][(g * 16 + lrow) * 64 + ((quad ^ (lrow & 7)) << 3)], pf0, o);
            o = MFMA16(*(const bf16x8*)&Vs[cur][(g * 16 + lrow) * 64 + (((4 + quad) ^ (lrow & 7)) << 3)], pf1, o);
            oacc[g] = o;
        }
        __builtin_amdgcn_s_setprio(0);

        // write next tile into the other buffer (its readers finished before
        // the previous iteration's barrier)
        if (more) {
            *(bf16x8*)&Ks[nxt][kRow * 128 + ksw] = nk0;
            *(bf16x8*)&Ks[nxt][(32 + kRow) * 128 + ksw] = nk1;
            *(bf16x8*)&Vs[nxt][vRow * 64 + vsw] = nv0;
            *(bf16x8*)&Vs[nxt][(64 + vRow) * 64 + vsw] = nv1;
        }
        __syncthreads();
    }

    // unnormalized partials: Ob[q*128 + dh] (indexed by LOGICAL blk)
    float* Ob = Opart + (size_t)blk * 16384;
#pragma unroll
    for (int g = 0; g < 8; g++)
        *(f32x4*)&Ob[(wave * 16 + lrow) * 128 + g * 16 + quad * 4] = oacc[g];
    if (quad == 0) {
        const int row = blk * 128 + wave * 16 + lrow;
        Mpart[row] = mrow;
        Lpart[row] = lsum;
    }
}

// ---------------------------------------------------------------------------
// Combine 4 split partials -> obuf (B,Q,H,128) bf16.
// grid 256 (full CU coverage), XCD-affine: physical p -> xcd=p&7,
// c = xcd*16 + ((p>>3)>>1), half = (p>>3)&1 — block lands on the XCD whose
// L2 holds its 4 split partials (attn chunking put lg=c*4+s on XCD c>>4).
// 512 threads: 64 rows x 8 col-groups of 16.
// ---------------------------------------------------------------------------
__global__ __launch_bounds__(512) void combine_attn(const float* __restrict__ Opart,
                                                    const float* __restrict__ Mpart,
                                                    const float* __restrict__ Lpart,
                                                    u16* __restrict__ ob) {
    const int p = blockIdx.x;
    const int xcd = p & 7, idx = p >> 3;
    const int c = xcd * 16 + (idx >> 1), half = idx & 1;   // c in [0,128)
    const int qt = c & 3, h = (c >> 2) & 7, b = c >> 5;
    const int lr = half * 64 + (threadIdx.x >> 3);
    const int cg = (threadIdx.x & 7) * 16;
    float ms[4], w[4];
    float m = -1e30f;
#pragma unroll
    for (int s = 0; s < 4; s++) { ms[s] = Mpart[(c * 4 + s) * 128 + lr]; m = fmaxf(m, ms[s]); }
    float l = 0.f;
#pragma unroll
    for (int s = 0; s < 4; s++) { w[s] = __expf(ms[s] - m); l += w[s] * Lpart[(c * 4 + s) * 128 + lr]; }
    const float inv = 1.f / l;
#pragma unroll
    for (int s = 0; s < 4; s++) w[s] *= inv;
    const size_t orow = ((size_t)(b * 512 + qt * 128 + lr) * 8 + h) << 7;
#pragma unroll
    for (int j = 0; j < 2; j++) {
        f32x4 a0 = {0.f, 0.f, 0.f, 0.f}, a1 = a0;
#pragma unroll
        for (int s = 0; s < 4; s++) {
            const f32x4* pp = (const f32x4*)(Opart + ((size_t)(c * 4 + s)) * 16384 + (size_t)lr * 128 + cg + j * 8);
            a0 += pp[0] * w[s];
            a1 += pp[1] * w[s];
        }
        u16x8 v;
#pragma unroll
        for (int i = 0; i < 4; i++) { v[i] = f2bf(a0[i]); v[4 + i] = f2bf(a1[i]); }
        *(u16x8*)&ob[orow + cg + j * 8] = v;
    }
}

// ---------------------------------------------------------------------------
extern "C" void kernel_launch(void* const* d_in, const int* in_sizes, int n_in,
                              void* d_out, int out_size, void* d_ws, size_t ws_size,
                              hipStream_t stream) {
    const float* inq   = (const float*)d_in[0];
    const float* inkv  = (const float*)d_in[1];
    const float* Wq    = (const float*)d_in[2];
    const float* Wkv   = (const float*)d_in[3];
    const float* Wproj = (const float*)d_in[4];
    const float* bproj = (const float*)d_in[5];
    float* out = (float*)d_out;

    u16* WqT    = (u16*)d_ws;                          // 1M elems
    u16* WkvT   = WqT + (size_t)1024 * 1024;           // 2M
    u16* WprojT = WkvT + (size_t)2048 * 1024;          // 1M
    u16* Aq     = WprojT + (size_t)1024 * 1024;        // 2M   bf16(inputs_q); dead after q-gemm
    u16* Akv    = Aq + (size_t)2048 * 1024;            // 16M  bf16(inputs_kv); dead after kv-gemm
    u16* qbuf   = Akv + (size_t)16384 * 1024;          // 2M   (B,Q,H,DH)
    u16* kvbuf  = qbuf + (size_t)2048 * 1024;          // 32M  (B,K,H,2DH) K-half valid
    u16* vTbuf  = kvbuf + (size_t)16384 * 2048;        // 16M  (B,H,DH,K)
    u16* obuf   = vTbuf + (size_t)32 * 128 * 4096;     // 2M   (B,Q,H,DH)

    float* Opart = (float*)Akv;                        // 512*16384 f32 = 32 MB
    float* Mpart = (float*)Aq;                         // 64K f32
    float* Lpart = Mpart + 65536;                      // 64K f32

    prep_all<<<10240, 256, 0, stream>>>(inq, Aq, inkv, Akv, Wq, WqT, Wkv, WkvT, Wproj, WprojT);

    gemm_bt<false, 64><<<16 * 16, 256, 0, stream>>>(Aq, WqT, qbuf, nullptr, 2048, 1024, 1024);
    gemm_kv256<<<512, 512, 0, stream>>>(Akv, WkvT, kvbuf, vTbuf);

    flash_attn_split<<<512, 512, 0, stream>>>(qbuf, kvbuf, vTbuf, Opart, Mpart, Lpart);
    combine_attn<<<256, 512, 0, stream>>>(Opart, Mpart, Lpart, obuf);

    gemm_bt<true, 64><<<16 * 16, 256, 0, stream>>>(obuf, WprojT, (void*)out, bproj, 2048, 1024, 1024);
}